// Round 3
// baseline (108.500 us; speedup 1.0000x reference)
//
#include <hip/hip_runtime.h>
#include <math.h>

// DLP loss: ce(scores,target) + 25 * sum_i sum_{k<m_i} ||f_i - f_{nbr_k}/m_i||^2
// m_i = min(#same-label (excl self), 20), neighbors by eps-shifted L1 distance.
//
// R10 NOTE: budget model: 105.9 = 41.5 (harness 256MB ws poison, its own
// HBM roofline) + ~35-40 fixed reset/launch + ~20 kernels+gaps. dist was the
// largest kernel and UNDER-PARTITIONED: 161 working blocks on 256 CUs, each
// serially executing ~4096 VALU insts (3.4 us floor). This round splits each
// (tile, K-half) into two ROW-halves -> 4 blocks/tile, 8 outputs/thread
// (2x4 blocking), halving per-block critical path; 1288 working waves.
// Dc layout and per-output accumulation order unchanged (absmax stays 0).
// R9 lesson kept: no device fences in wide kernels; finalize is its own
// 1-block kernel (inter-kernel barrier does coherence once, not 2048x).
//
//  K0 setup_kernel    : 1 block. stable class-sort -> perm, cls_start, tile tab.
//  K1 dist_kernel     : 4 blocks per class-tile (K-half x row-half), 2x4 reg
//                       blocking, b128 LDS reads, eps folded into A staging,
//                       mirror-store off-diagonal tiles. Partials -> Dc[kh].
//                       Last block (gridDim-1) computes CE -> P[N].
//  K2 select_kernel   : 1 wave/slot, sums the two K-half partials per cell,
//                       <=20 butterfly argmin extractions, contribution -> P.
//  K3 finalize_kernel : 1 block. out[0] = sum(P[0..N)) + P[N].

constexpr float EPS      = 1e-6f;
constexpr int   KSEL     = 20;
constexpr float LAM_HALF = 25.0f;   // 50 * 0.5
constexpr int   NCLS     = 8;

#define MAXC 512   // padded class-local row length (max class size << 512)
#define LDP  68    // LDS row stride (words): A broadcast, B 2-way (free)

__device__ __forceinline__ float finf() { return __builtin_inff(); }

// meta layout (ints), placed after Dc in ws:
//   [0, N)      perm: slot -> original row (class-grouped, index-ascending)
//   [N, N+9)    cls_start (exclusive prefix, cls_start[8] = N)
//   [N+16]      n_tiles
//   [N+32, ...) tile_tab: (class<<16)|(bi<<8)|bj, bi<=bj  (<=528 entries)

// ---------------- K0: stable class-sort + tile table ----------------
__global__ __launch_bounds__(256) void setup_kernel(const int* __restrict__ T,
                                                    int N, int* __restrict__ meta) {
    __shared__ int cnt[256 * NCLS];   // 8 KB
    __shared__ int cstart[NCLS + 1];
    const int tid = threadIdx.x;
    const int per = N / 256;          // 8 @ N=2048

    int lc[NCLS];
    int myT[16];
#pragma unroll
    for (int c = 0; c < NCLS; ++c) lc[c] = 0;
    for (int q = 0; q < per; ++q) {
        int t = T[tid * per + q];
        myT[q] = t;
        ++lc[t];
    }
#pragma unroll
    for (int c = 0; c < NCLS; ++c) cnt[tid * NCLS + c] = lc[c];
    __syncthreads();

    // per-class exclusive scan over the 256 thread-counts.
    // group g (32 lanes) owns class g; width-32 shfl scans, 8 chunks of 32.
    {
        const int g = tid >> 5, l = tid & 31;
        int carry = 0;
        for (int q = 0; q < 256; q += 32) {
            int v = cnt[(q + l) * NCLS + g];
            int x = v;
#pragma unroll
            for (int o = 1; o < 32; o <<= 1) {
                int y = __shfl_up(x, o, 32);
                if (l >= o) x += y;
            }
            cnt[(q + l) * NCLS + g] = carry + (x - v);   // exclusive prefix
            carry += __shfl(x, 31, 32);                  // chunk total
        }
        if (l == 31) cstart[g] = carry;                  // class totals (temp)
    }
    __syncthreads();
    if (tid == 0) {
        int tot[NCLS], acc = 0;
        for (int c = 0; c < NCLS; ++c) tot[c] = cstart[c];
        for (int c = 0; c < NCLS; ++c) { cstart[c] = acc; acc += tot[c]; }
        cstart[NCLS] = acc;           // == N
        for (int c = 0; c <= NCLS; ++c) meta[N + c] = cstart[c];
        // per-class upper-triangle 64-tile table
        int nt = 0;
        for (int c = 0; c < NCLS; ++c) {
            int nb = (tot[c] + 63) >> 6;
            for (int bi = 0; bi < nb; ++bi)
                for (int bj = bi; bj < nb; ++bj)
                    meta[N + 32 + nt++] = (c << 16) | (bi << 8) | bj;
        }
        meta[N + 16] = nt;
    }
    __syncthreads();

    // stable scatter: thread t owns contiguous rows [t*per, (t+1)*per)
    int rc[NCLS];
#pragma unroll
    for (int c = 0; c < NCLS; ++c) rc[c] = 0;
    for (int q = 0; q < per; ++q) {
        int t = myT[q];
        int pos = cstart[t] + cnt[tid * NCLS + t] + rc[t]++;
        meta[pos] = tid * per + q;
    }
}

// ---------------- K1: per-class masked pairwise eps-shifted L1 + CE ----------------
// block = (tile, K-half kh, row-half rh). Rows [i0+rh*32, +32), cols [j0, +64),
// channels [kh*128, +128) -> Dc_h. Diag stored +inf in both halves (inf+inf=inf).
// Block gridDim-1 instead computes cross-entropy -> P[N] (overlaps tile work).
__global__ __launch_bounds__(256) void dist_kernel(const float* __restrict__ F,
                                                   const int* __restrict__ meta,
                                                   float* __restrict__ Dc,
                                                   const float* __restrict__ scores,
                                                   const int* __restrict__ target,
                                                   float* __restrict__ P,
                                                   int N, int C, int NC) {
    if (blockIdx.x == gridDim.x - 1) {
        // ---- cross-entropy (mean) -> P[N]; independent of meta/Dc ----
        const int tid = threadIdx.x;
        float ce = 0.f;
        for (int r = tid; r < N; r += 256) {
            const float* sc = scores + (size_t)r * NC;
            float mx = -3.4e38f;
            for (int c = 0; c < NC; ++c) mx = fmaxf(mx, sc[c]);
            float sum = 0.f;
            for (int c = 0; c < NC; ++c) sum += __expf(sc[c] - mx);
            ce += mx + __logf(sum) - sc[target[r]];
        }
        __shared__ float redc[4];
        for (int o = 32; o > 0; o >>= 1) ce += __shfl_down(ce, o, 64);
        int wid = tid >> 6, lane = tid & 63;
        if (lane == 0) redc[wid] = ce;
        __syncthreads();
        if (tid == 0)
            P[N] = (redc[0] + redc[1] + redc[2] + redc[3]) / (float)N;
        return;
    }

    const int nt = meta[N + 16];
    const int t  = blockIdx.x >> 2;
    if (t >= nt) return;
    const int kh = (blockIdx.x >> 1) & 1;
    const int rh = blockIdx.x & 1;
    const int e    = meta[N + 32 + t];
    const int c    = e >> 16, bi = (e >> 8) & 255, bj = e & 255;
    const int base = meta[N + c];
    const int ncls = meta[N + c + 1] - base;
    const int i0 = bi * 64 + rh * 32, j0 = bj * 64;
    const bool mirror = (bi != bj);
    float* __restrict__ Dh = Dc + (size_t)kh * N * MAXC;

    __shared__ float As[32 * LDP];
    __shared__ float Bs[64 * LDP];
    __shared__ int gi[32], gj[64];

    const int tid = threadIdx.x;
    const int tx = tid & 15, ty = tid >> 4;

    if (tid < 32)                     gi[tid]      = meta[base + min(i0 + tid, ncls - 1)];
    else if (tid >= 64 && tid < 128)  gj[tid - 64] = meta[base + min(j0 + (tid - 64), ncls - 1)];
    __syncthreads();

    float acc[2][4];
#pragma unroll
    for (int r = 0; r < 2; ++r)
#pragma unroll
        for (int s = 0; s < 4; ++s) acc[r][s] = 0.f;

    const int ck0 = kh * (C / 2);
    for (int ck = ck0; ck < ck0 + C / 2; ck += 64) {
        // stage A: 32 rows x 64 ch = 512 float4 (2/thread), eps folded in
#pragma unroll
        for (int it = 0; it < 2; ++it) {
            int slot = tid + it * 256;
            int row  = slot >> 4;
            int c4   = (slot & 15) << 2;
            float4 av = *(const float4*)&F[(size_t)gi[row] * C + ck + c4];
            av.x += EPS; av.y += EPS; av.z += EPS; av.w += EPS;
            *(float4*)&As[row * LDP + c4] = av;
        }
        // stage B: 64 rows x 64 ch = 1024 float4 (4/thread)
#pragma unroll
        for (int it = 0; it < 4; ++it) {
            int slot = tid + it * 256;
            int row  = slot >> 4;
            int c4   = (slot & 15) << 2;
            *(float4*)&Bs[row * LDP + c4] =
                *(const float4*)&F[(size_t)gj[row] * C + ck + c4];
        }
        __syncthreads();
#pragma unroll 4
        for (int c4 = 0; c4 < 64; c4 += 4) {
            float4 a[2], b[4];
#pragma unroll
            for (int r = 0; r < 2; ++r) a[r] = *(const float4*)&As[(ty * 2 + r) * LDP + c4];
#pragma unroll
            for (int s = 0; s < 4; ++s) b[s] = *(const float4*)&Bs[(tx + 16 * s) * LDP + c4];
#pragma unroll
            for (int r = 0; r < 2; ++r)
#pragma unroll
                for (int s = 0; s < 4; ++s) {
                    acc[r][s] += (fabsf(a[r].x - b[s].x) + fabsf(a[r].y - b[s].y))
                               + (fabsf(a[r].z - b[s].z) + fabsf(a[r].w - b[s].w));
                }
        }
        __syncthreads();
    }

#pragma unroll
    for (int r = 0; r < 2; ++r) {
        const int il = i0 + ty * 2 + r;
        if (il >= ncls) continue;
#pragma unroll
        for (int s = 0; s < 4; ++s) {
            const int jl = j0 + tx + 16 * s;
            if (jl >= ncls) continue;
            float val = (il != jl) ? acc[r][s] : finf();
            Dh[(size_t)(base + il) * MAXC + jl] = val;
            if (mirror) Dh[(size_t)(base + jl) * MAXC + il] = val;  // eps asym << tol
        }
    }
}

// ---------------- K2: per-slot top-20 + contribution -> P[slot] ----------------
// one wave per class-sorted slot; lane l holds local cols {4l..4l+3, 256+4l..}
__global__ __launch_bounds__(64) void select_kernel(const float* __restrict__ F,
                                                    const float* __restrict__ Dc,
                                                    const int* __restrict__ meta,
                                                    float* __restrict__ P,
                                                    int N, int C) {
    __shared__ int ssel[KSEL];
    const int s    = blockIdx.x;
    const int lane = threadIdx.x;

    int c = 0;
#pragma unroll
    for (int q = 1; q <= NCLS; ++q) c += (s >= meta[N + q]) ? 1 : 0;
    const int base = meta[N + c];
    const int ncls = meta[N + c + 1] - base;
    const float4* drow0 = (const float4*)(Dc + (size_t)s * MAXC);
    const float4* drow1 = (const float4*)(Dc + (size_t)(N + s) * MAXC);

    float v[8];
#pragma unroll
    for (int q = 0; q < 2; ++q) {
        float4 t0 = drow0[q * 64 + lane];
        float4 t1 = drow1[q * 64 + lane];
        int col = q * 256 + 4 * lane;   // unwritten pad is poison -> mask it
        v[q * 4 + 0] = (col + 0 < ncls) ? (t0.x + t1.x) : finf();
        v[q * 4 + 1] = (col + 1 < ncls) ? (t0.y + t1.y) : finf();
        v[q * 4 + 2] = (col + 2 < ncls) ? (t0.z + t1.z) : finf();
        v[q * 4 + 3] = (col + 3 < ncls) ? (t0.w + t1.w) : finf();
    }

    const int m = min(ncls - 1, KSEL);

    float lmin = finf();
#pragma unroll
    for (int i = 0; i < 8; ++i) lmin = fminf(lmin, v[i]);

    int mx = 0;
    for (int k = 0; k < m; ++k) {
        float w = lmin;
#pragma unroll
        for (int o = 1; o < 64; o <<= 1) w = fminf(w, __shfl_xor(w, o, 64));
        if (!(w < 1e37f)) break;        // paranoia; finite count >= m by construction
        unsigned long long mask = __ballot(lmin == w);
        int winner = (int)__builtin_ctzll(mask);
        if (lane == winner) {
            bool found = false;
            int  jl = 0;
#pragma unroll
            for (int i = 0; i < 8; ++i) {
                bool hit = !found && (v[i] == w);
                if (hit) { jl = (i >> 2) * 256 + 4 * lane + (i & 3); v[i] = finf(); found = true; }
            }
            ssel[k] = jl;
            float nm = finf();
#pragma unroll
            for (int i = 0; i < 8; ++i) nm = fminf(nm, v[i]);
            lmin = nm;
        }
        ++mx;
    }
    __syncthreads();

    float total = 0.f;
    if (mx > 0) {
        const float inv = 1.f / (float)m;     // reference divides by len(nums)=m
        const int   gi  = meta[s];
        float4 fi = ((const float4*)(F + (size_t)gi * C))[lane];
        float acc = 0.f;
        for (int k = 0; k < mx; ++k) {
            const int gj = meta[base + ssel[k]];
            float4 fj = ((const float4*)(F + (size_t)gj * C))[lane];
            float dx = fi.x - fj.x * inv;
            float dy = fi.y - fj.y * inv;
            float dz = fi.z - fj.z * inv;
            float dw = fi.w - fj.w * inv;
            acc += (dx * dx + dy * dy) + (dz * dz + dw * dw);
        }
        for (int o = 32; o > 0; o >>= 1) acc += __shfl_down(acc, o, 64);
        total = LAM_HALF * acc;
    }
    if (lane == 0) P[s] = total;
}

// ---------------- K3: out[0] = sum(P[0..N)) + P[N] (CE from K1) ----------------
__global__ __launch_bounds__(256) void finalize_kernel(const float* __restrict__ P,
                                                       float* __restrict__ out,
                                                       int N) {
    const int tid = threadIdx.x;
    float dg = 0.f;
    for (int r = tid; r < N; r += 256) dg += P[r];
    __shared__ float red[4];
    for (int o = 32; o > 0; o >>= 1) dg += __shfl_down(dg, o, 64);
    int wid = tid >> 6, lane = tid & 63;
    if (lane == 0) red[wid] = dg;
    __syncthreads();
    if (tid == 0) out[0] = red[0] + red[1] + red[2] + red[3] + P[N];
}

extern "C" void kernel_launch(void* const* d_in, const int* in_sizes, int n_in,
                              void* d_out, int out_size, void* d_ws, size_t ws_size,
                              hipStream_t stream) {
    const float* feature = (const float*)d_in[0];
    const float* scores  = (const float*)d_in[1];
    const int*   target  = (const int*)d_in[2];
    const int N  = in_sizes[2];
    const int C  = in_sizes[0] / N;
    const int NC = in_sizes[1] / N;
    float* out = (float*)d_out;

    // ws layout: Dc (2 * N*MAXC floats = 8 MB) | meta (N+32+528 ints) | P (N+1 floats)
    float* Dc   = (float*)d_ws;
    int*   meta = (int*)((char*)d_ws + (size_t)2 * N * MAXC * sizeof(float));
    float* P    = (float*)((char*)d_ws + (size_t)2 * N * MAXC * sizeof(float) + 16384);

    setup_kernel<<<1, 256, 0, stream>>>(target, N, meta);

    // worst-case tile count: one class holding all N rows -> tri(N/64) = 528
    // 4 blocks per tile (K-half x row-half); +1 block: cross-entropy
    const int NB = N / 64;
    const int max_tiles = NB * (NB + 1) / 2;
    dist_kernel<<<max_tiles * 4 + 1, 256, 0, stream>>>(feature, meta, Dc,
                                                       scores, target, P, N, C, NC);

    select_kernel<<<N, 64, 0, stream>>>(feature, Dc, meta, P, N, C);

    finalize_kernel<<<1, 256, 0, stream>>>(P, out, N);
}

// Round 4
// 103.145 us; speedup vs baseline: 1.0519x; 1.0519x over previous
//
#include <hip/hip_runtime.h>
#include <math.h>

// DLP loss: ce(scores,target) + 25 * sum_i sum_{k<m_i} ||f_i - f_{nbr_k}/m_i||^2
// m_i = min(#same-label (excl self), 20), neighbors by eps-shifted L1 distance.
//
// R11 NOTE: R10's dist row-half split was neutral-to-negative (doubled B-tile
// staging + dispatch count canceled the critical-path halving) -> reverted to
// R9's 2-blocks-per-tile dist (verified 105.9 us total). The largest
// CONTROLLABLE item is select (+finalize): ~23.5 us by R8/R9 subtraction.
// Its contribution loop was 20 serially-dependent global RTTs
// (ssel[k]->meta->F-row per k, ~300-400 cyc each). This round batches it:
// all ssel reads, then 20 independent meta loads, then 20 independent F-row
// float4 loads + FMA (full unroll over compile-time KSEL). Accumulation
// order unchanged for valid k; invalid k adds exact 0.0f (absmax stays 0).
// R9 lesson kept: no device fences in wide kernels; finalize is its own
// 1-block kernel (inter-kernel barrier does coherence once, not 2048x).
//
//  K0 setup_kernel    : 1 block. stable class-sort -> perm, cls_start, tile tab.
//  K1 dist_kernel     : 2 blocks per class-tile (K-halves), 4x4 reg blocking,
//                       b128 LDS reads, eps folded into A staging, mirror-store
//                       off-diagonal tiles. Partials -> Dc[kh] (2 x 4 MB).
//                       Last block (gridDim-1) computes CE -> P[N].
//  K2 select_kernel   : 1 wave/slot, sums the two K-half partials per cell,
//                       <=20 butterfly argmin extractions, batched-ILP
//                       contribution -> P.
//  K3 finalize_kernel : 1 block. out[0] = sum(P[0..N)) + P[N].

constexpr float EPS      = 1e-6f;
constexpr int   KSEL     = 20;
constexpr float LAM_HALF = 25.0f;   // 50 * 0.5
constexpr int   NCLS     = 8;

#define MAXC 512   // padded class-local row length (max class size << 512)
#define LDP  68    // LDS row stride (words): A broadcast, B 2-way (free)

__device__ __forceinline__ float finf() { return __builtin_inff(); }

// meta layout (ints), placed after Dc in ws:
//   [0, N)      perm: slot -> original row (class-grouped, index-ascending)
//   [N, N+9)    cls_start (exclusive prefix, cls_start[8] = N)
//   [N+16]      n_tiles
//   [N+32, ...) tile_tab: (class<<16)|(bi<<8)|bj, bi<=bj  (<=528 entries)

// ---------------- K0: stable class-sort + tile table ----------------
__global__ __launch_bounds__(256) void setup_kernel(const int* __restrict__ T,
                                                    int N, int* __restrict__ meta) {
    __shared__ int cnt[256 * NCLS];   // 8 KB
    __shared__ int cstart[NCLS + 1];
    const int tid = threadIdx.x;
    const int per = N / 256;          // 8 @ N=2048

    int lc[NCLS];
    int myT[16];
#pragma unroll
    for (int c = 0; c < NCLS; ++c) lc[c] = 0;
    for (int q = 0; q < per; ++q) {
        int t = T[tid * per + q];
        myT[q] = t;
        ++lc[t];
    }
#pragma unroll
    for (int c = 0; c < NCLS; ++c) cnt[tid * NCLS + c] = lc[c];
    __syncthreads();

    // per-class exclusive scan over the 256 thread-counts.
    // group g (32 lanes) owns class g; width-32 shfl scans, 8 chunks of 32.
    {
        const int g = tid >> 5, l = tid & 31;
        int carry = 0;
        for (int q = 0; q < 256; q += 32) {
            int v = cnt[(q + l) * NCLS + g];
            int x = v;
#pragma unroll
            for (int o = 1; o < 32; o <<= 1) {
                int y = __shfl_up(x, o, 32);
                if (l >= o) x += y;
            }
            cnt[(q + l) * NCLS + g] = carry + (x - v);   // exclusive prefix
            carry += __shfl(x, 31, 32);                  // chunk total
        }
        if (l == 31) cstart[g] = carry;                  // class totals (temp)
    }
    __syncthreads();
    if (tid == 0) {
        int tot[NCLS], acc = 0;
        for (int c = 0; c < NCLS; ++c) tot[c] = cstart[c];
        for (int c = 0; c < NCLS; ++c) { cstart[c] = acc; acc += tot[c]; }
        cstart[NCLS] = acc;           // == N
        for (int c = 0; c <= NCLS; ++c) meta[N + c] = cstart[c];
        // per-class upper-triangle 64-tile table
        int nt = 0;
        for (int c = 0; c < NCLS; ++c) {
            int nb = (tot[c] + 63) >> 6;
            for (int bi = 0; bi < nb; ++bi)
                for (int bj = bi; bj < nb; ++bj)
                    meta[N + 32 + nt++] = (c << 16) | (bi << 8) | bj;
        }
        meta[N + 16] = nt;
    }
    __syncthreads();

    // stable scatter: thread t owns contiguous rows [t*per, (t+1)*per)
    int rc[NCLS];
#pragma unroll
    for (int c = 0; c < NCLS; ++c) rc[c] = 0;
    for (int q = 0; q < per; ++q) {
        int t = myT[q];
        int pos = cstart[t] + cnt[tid * NCLS + t] + rc[t]++;
        meta[pos] = tid * per + q;
    }
}

// ---------------- K1: per-class masked pairwise eps-shifted L1 + CE ----------------
// block = (tile, K-half). Partial over c in [kh*128, kh*128+128) -> Dc_h.
// Dc_h[slot][jl] partial; diag stored +inf in both halves (inf+inf = inf).
// Block gridDim-1 instead computes cross-entropy -> P[N] (overlaps tile work).
__global__ __launch_bounds__(256) void dist_kernel(const float* __restrict__ F,
                                                   const int* __restrict__ meta,
                                                   float* __restrict__ Dc,
                                                   const float* __restrict__ scores,
                                                   const int* __restrict__ target,
                                                   float* __restrict__ P,
                                                   int N, int C, int NC) {
    if (blockIdx.x == gridDim.x - 1) {
        // ---- cross-entropy (mean) -> P[N]; independent of meta/Dc ----
        const int tid = threadIdx.x;
        float ce = 0.f;
        for (int r = tid; r < N; r += 256) {
            const float* sc = scores + (size_t)r * NC;
            float mx = -3.4e38f;
            for (int c = 0; c < NC; ++c) mx = fmaxf(mx, sc[c]);
            float sum = 0.f;
            for (int c = 0; c < NC; ++c) sum += __expf(sc[c] - mx);
            ce += mx + __logf(sum) - sc[target[r]];
        }
        __shared__ float redc[4];
        for (int o = 32; o > 0; o >>= 1) ce += __shfl_down(ce, o, 64);
        int wid = tid >> 6, lane = tid & 63;
        if (lane == 0) redc[wid] = ce;
        __syncthreads();
        if (tid == 0)
            P[N] = (redc[0] + redc[1] + redc[2] + redc[3]) / (float)N;
        return;
    }

    const int nt = meta[N + 16];
    const int t  = blockIdx.x >> 1;
    if (t >= nt) return;
    const int kh = blockIdx.x & 1;
    const int e    = meta[N + 32 + t];
    const int c    = e >> 16, bi = (e >> 8) & 255, bj = e & 255;
    const int base = meta[N + c];
    const int ncls = meta[N + c + 1] - base;
    const int i0 = bi * 64, j0 = bj * 64;
    const bool mirror = (bi != bj);
    float* __restrict__ Dh = Dc + (size_t)kh * N * MAXC;

    __shared__ float As[64 * LDP];
    __shared__ float Bs[64 * LDP];
    __shared__ int gi[64], gj[64];

    const int tid = threadIdx.x;
    const int tx = tid & 15, ty = tid >> 4;

    if (tid < 64)       gi[tid]      = meta[base + min(i0 + tid, ncls - 1)];
    else if (tid < 128) gj[tid - 64] = meta[base + min(j0 + (tid - 64), ncls - 1)];
    __syncthreads();

    float acc[4][4];
#pragma unroll
    for (int r = 0; r < 4; ++r)
#pragma unroll
        for (int s = 0; s < 4; ++s) acc[r][s] = 0.f;

    const int ck0 = kh * (C / 2);
    for (int ck = ck0; ck < ck0 + C / 2; ck += 64) {
#pragma unroll
        for (int it = 0; it < 4; ++it) {
            int slot = tid + it * 256;
            int row  = slot >> 4;
            int c4   = (slot & 15) << 2;
            float4 av = *(const float4*)&F[(size_t)gi[row] * C + ck + c4];
            av.x += EPS; av.y += EPS; av.z += EPS; av.w += EPS;
            *(float4*)&As[row * LDP + c4] = av;
            *(float4*)&Bs[row * LDP + c4] =
                *(const float4*)&F[(size_t)gj[row] * C + ck + c4];
        }
        __syncthreads();
#pragma unroll 4
        for (int c4 = 0; c4 < 64; c4 += 4) {
            float4 a[4], b[4];
#pragma unroll
            for (int r = 0; r < 4; ++r) a[r] = *(const float4*)&As[(ty * 4 + r) * LDP + c4];
#pragma unroll
            for (int s = 0; s < 4; ++s) b[s] = *(const float4*)&Bs[(tx + 16 * s) * LDP + c4];
#pragma unroll
            for (int r = 0; r < 4; ++r)
#pragma unroll
                for (int s = 0; s < 4; ++s) {
                    acc[r][s] += (fabsf(a[r].x - b[s].x) + fabsf(a[r].y - b[s].y))
                               + (fabsf(a[r].z - b[s].z) + fabsf(a[r].w - b[s].w));
                }
        }
        __syncthreads();
    }

#pragma unroll
    for (int r = 0; r < 4; ++r) {
        const int il = i0 + ty * 4 + r;
        if (il >= ncls) continue;
#pragma unroll
        for (int s = 0; s < 4; ++s) {
            const int jl = j0 + tx + 16 * s;
            if (jl >= ncls) continue;
            float val = (il != jl) ? acc[r][s] : finf();
            Dh[(size_t)(base + il) * MAXC + jl] = val;
            if (mirror) Dh[(size_t)(base + jl) * MAXC + il] = val;  // eps asym << tol
        }
    }
}

// ---------------- K2: per-slot top-20 + contribution -> P[slot] ----------------
// one wave per class-sorted slot; lane l holds local cols {4l..4l+3, 256+4l..}
// Contribution loop is fully unrolled with batched independent loads:
// phase 1: all ssel -> regs; phase 2: 20 independent meta loads;
// phase 3: 20 independent F-row float4 loads + FMA. Valid-k accumulation
// order identical to serial version; invalid k adds exact 0.0f.
__global__ __launch_bounds__(64) void select_kernel(const float* __restrict__ F,
                                                    const float* __restrict__ Dc,
                                                    const int* __restrict__ meta,
                                                    float* __restrict__ P,
                                                    int N, int C) {
    __shared__ int ssel[KSEL];
    const int s    = blockIdx.x;
    const int lane = threadIdx.x;

    int c = 0;
#pragma unroll
    for (int q = 1; q <= NCLS; ++q) c += (s >= meta[N + q]) ? 1 : 0;
    const int base = meta[N + c];
    const int ncls = meta[N + c + 1] - base;
    const float4* drow0 = (const float4*)(Dc + (size_t)s * MAXC);
    const float4* drow1 = (const float4*)(Dc + (size_t)(N + s) * MAXC);

    float v[8];
#pragma unroll
    for (int q = 0; q < 2; ++q) {
        float4 t0 = drow0[q * 64 + lane];
        float4 t1 = drow1[q * 64 + lane];
        int col = q * 256 + 4 * lane;   // unwritten pad is poison -> mask it
        v[q * 4 + 0] = (col + 0 < ncls) ? (t0.x + t1.x) : finf();
        v[q * 4 + 1] = (col + 1 < ncls) ? (t0.y + t1.y) : finf();
        v[q * 4 + 2] = (col + 2 < ncls) ? (t0.z + t1.z) : finf();
        v[q * 4 + 3] = (col + 3 < ncls) ? (t0.w + t1.w) : finf();
    }

    const int m = min(ncls - 1, KSEL);

    float lmin = finf();
#pragma unroll
    for (int i = 0; i < 8; ++i) lmin = fminf(lmin, v[i]);

    int mx = 0;
    for (int k = 0; k < m; ++k) {
        float w = lmin;
#pragma unroll
        for (int o = 1; o < 64; o <<= 1) w = fminf(w, __shfl_xor(w, o, 64));
        if (!(w < 1e37f)) break;        // paranoia; finite count >= m by construction
        unsigned long long mask = __ballot(lmin == w);
        int winner = (int)__builtin_ctzll(mask);
        if (lane == winner) {
            bool found = false;
            int  jl = 0;
#pragma unroll
            for (int i = 0; i < 8; ++i) {
                bool hit = !found && (v[i] == w);
                if (hit) { jl = (i >> 2) * 256 + 4 * lane + (i & 3); v[i] = finf(); found = true; }
            }
            ssel[k] = jl;
            float nm = finf();
#pragma unroll
            for (int i = 0; i < 8; ++i) nm = fminf(nm, v[i]);
            lmin = nm;
        }
        ++mx;
    }
    __syncthreads();

    float total = 0.f;
    if (mx > 0) {
        const float inv = 1.f / (float)m;     // reference divides by len(nums)=m
        const int   gi  = meta[s];
        float4 fi = ((const float4*)(F + (size_t)gi * C))[lane];

        // phase 1: local neighbor indices (clamped for k >= mx: safe in-range 0)
        int gjr[KSEL];
#pragma unroll
        for (int k = 0; k < KSEL; ++k) gjr[k] = (k < mx) ? ssel[k] : 0;
        // phase 2: global row indices (independent loads, batched in flight)
#pragma unroll
        for (int k = 0; k < KSEL; ++k) gjr[k] = meta[base + gjr[k]];
        // phase 3: independent F-row loads + FMA; valid-k order == old serial
        float acc = 0.f;
#pragma unroll
        for (int k = 0; k < KSEL; ++k) {
            float4 fj = ((const float4*)(F + (size_t)gjr[k] * C))[lane];
            float dx = fi.x - fj.x * inv;
            float dy = fi.y - fj.y * inv;
            float dz = fi.z - fj.z * inv;
            float dw = fi.w - fj.w * inv;
            float t  = (dx * dx + dy * dy) + (dz * dz + dw * dw);
            acc += (k < mx) ? t : 0.0f;
        }
        for (int o = 32; o > 0; o >>= 1) acc += __shfl_down(acc, o, 64);
        total = LAM_HALF * acc;
    }
    if (lane == 0) P[s] = total;
}

// ---------------- K3: out[0] = sum(P[0..N)) + P[N] (CE from K1) ----------------
__global__ __launch_bounds__(256) void finalize_kernel(const float* __restrict__ P,
                                                       float* __restrict__ out,
                                                       int N) {
    const int tid = threadIdx.x;
    float dg = 0.f;
    for (int r = tid; r < N; r += 256) dg += P[r];
    __shared__ float red[4];
    for (int o = 32; o > 0; o >>= 1) dg += __shfl_down(dg, o, 64);
    int wid = tid >> 6, lane = tid & 63;
    if (lane == 0) red[wid] = dg;
    __syncthreads();
    if (tid == 0) out[0] = red[0] + red[1] + red[2] + red[3] + P[N];
}

extern "C" void kernel_launch(void* const* d_in, const int* in_sizes, int n_in,
                              void* d_out, int out_size, void* d_ws, size_t ws_size,
                              hipStream_t stream) {
    const float* feature = (const float*)d_in[0];
    const float* scores  = (const float*)d_in[1];
    const int*   target  = (const int*)d_in[2];
    const int N  = in_sizes[2];
    const int C  = in_sizes[0] / N;
    const int NC = in_sizes[1] / N;
    float* out = (float*)d_out;

    // ws layout: Dc (2 * N*MAXC floats = 8 MB) | meta (N+32+528 ints) | P (N+1 floats)
    float* Dc   = (float*)d_ws;
    int*   meta = (int*)((char*)d_ws + (size_t)2 * N * MAXC * sizeof(float));
    float* P    = (float*)((char*)d_ws + (size_t)2 * N * MAXC * sizeof(float) + 16384);

    setup_kernel<<<1, 256, 0, stream>>>(target, N, meta);

    // worst-case tile count: one class holding all N rows -> tri(N/64) = 528
    // 2 blocks per tile (K-halves); +1 block: cross-entropy
    const int NB = N / 64;
    const int max_tiles = NB * (NB + 1) / 2;
    dist_kernel<<<max_tiles * 2 + 1, 256, 0, stream>>>(feature, meta, Dc,
                                                       scores, target, P, N, C, NC);

    select_kernel<<<N, 64, 0, stream>>>(feature, Dc, meta, P, N, C);

    finalize_kernel<<<1, 256, 0, stream>>>(P, out, N);
}